// Round 2
// baseline (865.449 us; speedup 1.0000x reference)
//
#include <hip/hip_runtime.h>
#include <hip/hip_bf16.h>
#include <stdint.h>

typedef __attribute__((ext_vector_type(8))) short bf16x8;
typedef __attribute__((ext_vector_type(4))) float f32x4;
typedef __attribute__((ext_vector_type(4))) unsigned short us4;

// XOR swizzle within a 32KB [256 rows][128B] tile: flip 16B-chunk bits 4-6 by row&7.
#define SWZ(L) ((L) ^ ((((L) >> 7) & 7) << 4))

__device__ __forceinline__ unsigned short f2b(float f) {
  union { float f; unsigned u; } u;
  u.f = f;
  unsigned r = u.u + 0x7fffu + ((u.u >> 16) & 1u);
  return (unsigned short)(r >> 16);
}

__device__ __forceinline__ void gload_lds16(const void* g, void* lds) {
  __builtin_amdgcn_global_load_lds(
      (const __attribute__((address_space(1))) unsigned int*)(uintptr_t)g,
      (__attribute__((address_space(3))) unsigned int*)(uintptr_t)lds,
      16, 0, 0);
}

// Stage half-tile h of the K-stream (h counts 4 halves per K-tile: A0,A1,B0,B1).
// LDS dest linear; global source pre-swizzled (involution) so swizzled reads see
// logical data (rule #21: both-sides-or-neither).
__device__ __forceinline__ void stage_half(
    const unsigned short* __restrict__ Ag, const unsigned short* __restrict__ Bg,
    long bm0, long bn0, long ldA, long ldB, char* lds, int h, int tid) {
  int T = h >> 2, q = h & 3;
  const unsigned short* mat = (q < 2) ? Ag : Bg;
  long row0 = (q < 2) ? bm0 : bn0;
  long ld = (q < 2) ? ldA : ldB;
  char* tile = lds + (long)(T & 1) * 65536 + (q >> 1) * 32768;
  int w = tid >> 6, lane = tid & 63;
#pragma unroll
  for (int j = 0; j < 2; ++j) {
    int P = (q & 1) * 16384 + j * 8192 + w * 1024 + lane * 16;
    int L = SWZ(P);
    const unsigned short* gp =
        mat + (row0 + (L >> 7)) * ld + (long)T * 64 + ((L & 127) >> 1);
    gload_lds16(gp, tile + (q & 1) * 16384 + j * 8192 + w * 1024);
  }
}

__device__ __forceinline__ void readA(const char* tA, int wr, int r, int g,
                                      bf16x8 (&aF)[8][2]) {
#pragma unroll
  for (int m = 0; m < 8; ++m)
#pragma unroll
    for (int s = 0; s < 2; ++s) {
      int L = (wr * 128 + m * 16 + r) * 128 + s * 64 + g * 16;
      aF[m][s] = *(const bf16x8*)(tA + SWZ(L));
    }
}

__device__ __forceinline__ void readB(const char* tB, int wc, int qn, int r, int g,
                                      bf16x8 (&bF)[2][2]) {
#pragma unroll
  for (int n = 0; n < 2; ++n)
#pragma unroll
    for (int s = 0; s < 2; ++s) {
      int L = (wc * 64 + (qn * 2 + n) * 16 + r) * 128 + s * 64 + g * 16;
      bF[n][s] = *(const bf16x8*)(tB + SWZ(L));
    }
}

template <int QM, int QN>
__device__ __forceinline__ void mfma_quad(f32x4 (&acc)[8][4], bf16x8 (&aF)[8][2],
                                          bf16x8 (&bF)[2][2]) {
#pragma unroll
  for (int s = 0; s < 2; ++s)
#pragma unroll
    for (int mm = 0; mm < 4; ++mm)
#pragma unroll
      for (int nn = 0; nn < 2; ++nn)
        acc[QM * 4 + mm][QN * 2 + nn] = __builtin_amdgcn_mfma_f32_16x16x32_bf16(
            aF[QM * 4 + mm][s], bF[nn][s], acc[QM * 4 + mm][QN * 2 + nn], 0, 0, 0);
}

#define SBAR() do { __builtin_amdgcn_s_barrier(); __builtin_amdgcn_sched_barrier(0); } while (0)

// 256x256 tile, BK=64, 8 waves (2M x 4N), 8-phase pipelined K-loop.
// Stage pointer runs 7 halves ahead; vmcnt(6) at K-tile boundaries (3 future
// halves = 6 loads allowed in flight); final boundary drains vmcnt(0).
__device__ __forceinline__ void gemm_core(
    const unsigned short* __restrict__ Ag, const unsigned short* __restrict__ Bg,
    long bm0, long bn0, long ldA, long ldB, int KT, char* lds,
    f32x4 (&acc)[8][4]) {
  int tid = threadIdx.x;
  int w = tid >> 6, lane = tid & 63;
  int wr = w >> 2, wc = w & 3;
  int r = lane & 15, g = lane >> 4;
  int totalH = KT * 4;
#pragma unroll
  for (int h = 0; h < 7; ++h)
    stage_half(Ag, Bg, bm0, bn0, ldA, ldB, lds, h, tid);
  asm volatile("s_waitcnt vmcnt(6)" ::: "memory");
  SBAR();

  bf16x8 aF[8][2], bF[2][2];
  int niter = KT >> 1;
  for (int it = 0; it < niter; ++it) {
    bool last = (it == niter - 1);
    int hb = it * 8 + 7;
#pragma unroll
    for (int c = 0; c < 2; ++c) {
      char* tA = lds + c * 65536;
      char* tB = tA + 32768;
      // ---- phase 0: all A frags + B quadrant 0; MFMA quad (0,0) ----
      readA(tA, wr, r, g, aF);
      readB(tB, wc, 0, r, g, bF);
      if (hb + c * 4 + 0 < totalH)
        stage_half(Ag, Bg, bm0, bn0, ldA, ldB, lds, hb + c * 4 + 0, tid);
      SBAR();
      __builtin_amdgcn_s_setprio(1);
      mfma_quad<0, 0>(acc, aF, bF);
      __builtin_amdgcn_s_setprio(0);
      asm volatile("s_waitcnt lgkmcnt(0)" ::: "memory");  // all head reads done
      __builtin_amdgcn_sched_barrier(0);
      SBAR();
      // ---- phase 1: MFMA quad (1,0) ----
      if (hb + c * 4 + 1 < totalH)
        stage_half(Ag, Bg, bm0, bn0, ldA, ldB, lds, hb + c * 4 + 1, tid);
      SBAR();
      __builtin_amdgcn_s_setprio(1);
      mfma_quad<1, 0>(acc, aF, bF);
      __builtin_amdgcn_s_setprio(0);
      SBAR();
      // ---- phase 2: B quadrant 1; MFMA quad (1,1) ----
      readB(tB, wc, 1, r, g, bF);
      if (hb + c * 4 + 2 < totalH)
        stage_half(Ag, Bg, bm0, bn0, ldA, ldB, lds, hb + c * 4 + 2, tid);
      SBAR();
      __builtin_amdgcn_s_setprio(1);
      mfma_quad<1, 1>(acc, aF, bF);
      __builtin_amdgcn_s_setprio(0);
      SBAR();
      // ---- phase 3: MFMA quad (0,1); K-tile boundary vmcnt ----
      if (hb + c * 4 + 3 < totalH)
        stage_half(Ag, Bg, bm0, bn0, ldA, ldB, lds, hb + c * 4 + 3, tid);
      SBAR();
      __builtin_amdgcn_s_setprio(1);
      mfma_quad<0, 1>(acc, aF, bF);
      __builtin_amdgcn_s_setprio(0);
      if (!last)
        asm volatile("s_waitcnt vmcnt(6)" ::: "memory");
      else if (c == 0)
        asm volatile("s_waitcnt vmcnt(0)" ::: "memory");
      SBAR();
    }
  }
}

// ---------------- GEMM1: qkv = x @ W^T + b (bf16 out) ----------------
__global__ __launch_bounds__(512, 2) void gemm1_qkv(
    const unsigned short* __restrict__ A, const unsigned short* __restrict__ Bm,
    const float* __restrict__ bias, unsigned short* __restrict__ C) {
  extern __shared__ char smem[];
  int bid = blockIdx.x;
  int s = (bid & 7) * 96 + (bid >> 3);  // XCD swizzle, 768 % 8 == 0
  long bm0 = (long)(s / 12) * 256;
  long bn0 = (long)(s % 12) * 256;
  f32x4 acc[8][4] = {};
  gemm_core(A, Bm, bm0, bn0, 1024, 1024, 16, smem, acc);
  int tid = threadIdx.x, w = tid >> 6, lane = tid & 63;
  int wr = w >> 2, wc = w & 3, r = lane & 15, g = lane >> 4;
#pragma unroll
  for (int n = 0; n < 4; ++n) {
    long col = bn0 + wc * 64 + n * 16 + r;
    float bv = bias[col];
#pragma unroll
    for (int m = 0; m < 8; ++m)
#pragma unroll
      for (int j = 0; j < 4; ++j) {
        long row = bm0 + wr * 128 + m * 16 + g * 4 + j;
        C[row * 3072 + col] = f2b(acc[m][n][j] + bv);
      }
  }
}

// ------------- GEMM2: scores = tril(q @ k^T) * inv_scale (bf16) -------------
__global__ __launch_bounds__(512, 2) void gemm2_scores(
    const unsigned short* __restrict__ qkv, unsigned short* __restrict__ scores,
    float inv_scale) {
  extern __shared__ char smem[];
  int bj = blockIdx.x, bi = blockIdx.y, b = blockIdx.z;
  if (bj > bi) return;
  const unsigned short* A = qkv + (long)b * 2048 * 3072;
  const unsigned short* Bm = A + 1024;
  long bm0 = (long)bi * 256, bn0 = (long)bj * 256;
  f32x4 acc[8][4] = {};
  gemm_core(A, Bm, bm0, bn0, 3072, 3072, 16, smem, acc);
  unsigned short* S = scores + (long)b * 2048 * 2048;
  int tid = threadIdx.x, w = tid >> 6, lane = tid & 63;
  int wr = w >> 2, wc = w & 3, r = lane & 15, g = lane >> 4;
#pragma unroll
  for (int n = 0; n < 4; ++n) {
    long col = bn0 + wc * 64 + n * 16 + r;
#pragma unroll
    for (int m = 0; m < 8; ++m)
#pragma unroll
      for (int j = 0; j < 4; ++j) {
        long row = bm0 + wr * 128 + m * 16 + g * 4 + j;
        float v = acc[m][n][j] * inv_scale;
        if (col > row) v = 0.0f;
        S[row * 2048 + col] = f2b(v);
      }
  }
}

// ---------------- GEMM3: y = scores @ v (f32 out, causal K) ----------------
__global__ __launch_bounds__(512, 2) void gemm3_y(
    const unsigned short* __restrict__ scores, const unsigned short* __restrict__ vT,
    float* __restrict__ out) {
  extern __shared__ char smem[];
  int bn = blockIdx.x, bi = blockIdx.y, b = blockIdx.z;
  const unsigned short* A = scores + (long)b * 2048 * 2048;
  const unsigned short* Bm = vT + (long)b * 1024 * 2048;
  long bm0 = (long)bi * 256, bn0 = (long)bn * 256;
  f32x4 acc[8][4] = {};
  gemm_core(A, Bm, bm0, bn0, 2048, 2048, (bi + 1) * 4, smem, acc);
  int tid = threadIdx.x, w = tid >> 6, lane = tid & 63;
  int wr = w >> 2, wc = w & 3, r = lane & 15, g = lane >> 4;
#pragma unroll
  for (int n = 0; n < 4; ++n) {
    long col = bn0 + wc * 64 + n * 16 + r;
#pragma unroll
    for (int m = 0; m < 8; ++m)
#pragma unroll
      for (int j = 0; j < 4; ++j) {
        long row = bm0 + wr * 128 + m * 16 + g * 4 + j;
        out[((long)b * 2048 + row) * 1024 + col] = acc[m][n][j];
      }
  }
}

// ---------------- f32 -> bf16 conversion ----------------
__global__ void cvt_f32_bf16(const float* __restrict__ in,
                             unsigned short* __restrict__ out, long n) {
  long i = ((long)blockIdx.x * blockDim.x + threadIdx.x) * 8;
  if (i + 8 > n) return;
  float4 a = *(const float4*)(in + i);
  float4 b = *(const float4*)(in + i + 4);
  bf16x8 o;
  o[0] = (short)f2b(a.x); o[1] = (short)f2b(a.y);
  o[2] = (short)f2b(a.z); o[3] = (short)f2b(a.w);
  o[4] = (short)f2b(b.x); o[5] = (short)f2b(b.y);
  o[6] = (short)f2b(b.z); o[7] = (short)f2b(b.w);
  *(bf16x8*)(out + i) = o;
}

// ---------------- transpose v: [b][t][d] -> [b][d][t] (bf16) ----------------
__global__ void transpose_v(const unsigned short* __restrict__ qkv,
                            unsigned short* __restrict__ vT) {
  __shared__ unsigned short tile[64][72];
  int t0 = blockIdx.x * 64, d0 = blockIdx.y * 64, b = blockIdx.z;
  int tid = threadIdx.x;
  int sub = tid & 15, grp = tid >> 4;
#pragma unroll
  for (int it = 0; it < 4; ++it) {
    int tt = it * 16 + grp;
    int dd = sub * 4;
    const unsigned short* src =
        qkv + ((long)(b * 2048 + t0 + tt)) * 3072 + 2048 + d0 + dd;
    *(us4*)&tile[tt][dd] = *(const us4*)src;
  }
  __syncthreads();
#pragma unroll
  for (int it = 0; it < 4; ++it) {
    int dd = it * 16 + grp;
    int ts = sub * 4;
    us4 o;
    o[0] = tile[ts + 0][dd];
    o[1] = tile[ts + 1][dd];
    o[2] = tile[ts + 2][dd];
    o[3] = tile[ts + 3][dd];
    *(us4*)(vT + ((long)b * 1024 + d0 + dd) * 2048 + t0 + ts) = o;
  }
}

// ---------------- LayerNorm (in-place on f32 out) ----------------
__global__ void ln_kernel(float* __restrict__ y, const float* __restrict__ wv,
                          const float* __restrict__ bv) {
  __shared__ float sm[4];
  long row = blockIdx.x;
  int tid = threadIdx.x;
  float4 v = *(const float4*)(y + row * 1024 + tid * 4);
  float s = v.x + v.y + v.z + v.w;
#pragma unroll
  for (int o = 32; o > 0; o >>= 1) s += __shfl_xor(s, o, 64);
  if ((tid & 63) == 0) sm[tid >> 6] = s;
  __syncthreads();
  float mu = (sm[0] + sm[1] + sm[2] + sm[3]) * (1.0f / 1024.0f);
  float dx = v.x - mu, dy = v.y - mu, dz = v.z - mu, dw = v.w - mu;
  float sq = dx * dx + dy * dy + dz * dz + dw * dw;
#pragma unroll
  for (int o = 32; o > 0; o >>= 1) sq += __shfl_xor(sq, o, 64);
  __syncthreads();
  if ((tid & 63) == 0) sm[tid >> 6] = sq;
  __syncthreads();
  float var = (sm[0] + sm[1] + sm[2] + sm[3]) * (1.0f / 1024.0f);
  float inv = rsqrtf(var + 1e-5f);
  float4 w4 = *(const float4*)(wv + tid * 4);
  float4 b4 = *(const float4*)(bv + tid * 4);
  float4 o4;
  o4.x = dx * inv * w4.x + b4.x;
  o4.y = dy * inv * w4.y + b4.y;
  o4.z = dz * inv * w4.z + b4.z;
  o4.w = dw * inv * w4.w + b4.w;
  *(float4*)(y + row * 1024 + tid * 4) = o4;
}

extern "C" void kernel_launch(void* const* d_in, const int* in_sizes, int n_in,
                              void* d_out, int out_size, void* d_ws, size_t ws_size,
                              hipStream_t stream) {
  const float* x = (const float*)d_in[0];
  const float* W = (const float*)d_in[1];
  const float* bq = (const float*)d_in[2];
  const float* lnw = (const float*)d_in[3];
  const float* lnb = (const float*)d_in[4];
  float* out = (float*)d_out;

  char* ws = (char*)d_ws;
  unsigned short* qkv = (unsigned short*)(ws);
  unsigned short* vT = (unsigned short*)(ws + 100663296L);
  unsigned short* sc = (unsigned short*)(ws + 134217728L);
  unsigned short* xb = (unsigned short*)(ws + 134217728L);
  unsigned short* Wb = (unsigned short*)(ws + 167772160L);

  const float inv_scale = 1.0f / sqrtf(1024.0f * 2048.0f);

  hipFuncSetAttribute((const void*)gemm1_qkv,
                      hipFuncAttributeMaxDynamicSharedMemorySize, 131072);
  hipFuncSetAttribute((const void*)gemm2_scores,
                      hipFuncAttributeMaxDynamicSharedMemorySize, 131072);
  hipFuncSetAttribute((const void*)gemm3_y,
                      hipFuncAttributeMaxDynamicSharedMemorySize, 131072);

  cvt_f32_bf16<<<8192, 256, 0, stream>>>(x, xb, 16384L * 1024);
  cvt_f32_bf16<<<1536, 256, 0, stream>>>(W, Wb, 3072L * 1024);
  gemm1_qkv<<<768, 512, 131072, stream>>>(xb, Wb, bq, qkv);
  transpose_v<<<dim3(32, 16, 8), 256, 0, stream>>>(qkv, vT);
  gemm2_scores<<<dim3(8, 8, 8), 512, 131072, stream>>>(qkv, sc, inv_scale);
  gemm3_y<<<dim3(4, 8, 8), 512, 131072, stream>>>(sc, vT, out);
  ln_kernel<<<16384, 256, 0, stream>>>(out, lnw, lnb);
}

// Round 3
// 849.082 us; speedup vs baseline: 1.0193x; 1.0193x over previous
//
#include <hip/hip_runtime.h>
#include <hip/hip_bf16.h>
#include <stdint.h>

typedef __attribute__((ext_vector_type(8))) short bf16x8;
typedef __attribute__((ext_vector_type(4))) float f32x4;
typedef __attribute__((ext_vector_type(4))) unsigned short us4;

// XOR swizzle within a 32KB [256 rows][128B] tile: flip byte-bits 4-6 by row&7.
#define SWZ(L) ((L) ^ ((((L) >> 7) & 7) << 4))

__device__ __forceinline__ unsigned short f2b(float f) {
  union { float f; unsigned u; } u;
  u.f = f;
  unsigned r = u.u + 0x7fffu + ((u.u >> 16) & 1u);
  return (unsigned short)(r >> 16);
}

__device__ __forceinline__ void gload_lds16(const void* g, void* lds) {
  __builtin_amdgcn_global_load_lds(
      (const __attribute__((address_space(1))) unsigned int*)(uintptr_t)g,
      (__attribute__((address_space(3))) unsigned int*)(uintptr_t)lds,
      16, 0, 0);
}

__device__ __forceinline__ void readA(const char* tA, int wr, int r, int g,
                                      bf16x8 (&aF)[8][2]) {
#pragma unroll
  for (int m = 0; m < 8; ++m)
#pragma unroll
    for (int s = 0; s < 2; ++s) {
      int L = (wr * 128 + m * 16 + r) * 128 + s * 64 + g * 16;
      aF[m][s] = *(const bf16x8*)(tA + SWZ(L));
    }
}

__device__ __forceinline__ void readB(const char* tB, int wc, int qn, int r, int g,
                                      bf16x8 (&bF)[2][2]) {
#pragma unroll
  for (int n = 0; n < 2; ++n)
#pragma unroll
    for (int s = 0; s < 2; ++s) {
      int L = (wc * 64 + (qn * 2 + n) * 16 + r) * 128 + s * 64 + g * 16;
      bF[n][s] = *(const bf16x8*)(tB + SWZ(L));
    }
}

template <int QM, int QN>
__device__ __forceinline__ void mfma_quad(f32x4 (&acc)[8][4], bf16x8 (&aF)[8][2],
                                          bf16x8 (&bF)[2][2]) {
#pragma unroll
  for (int s = 0; s < 2; ++s)
#pragma unroll
    for (int mm = 0; mm < 4; ++mm)
#pragma unroll
      for (int nn = 0; nn < 2; ++nn)
        acc[QM * 4 + mm][QN * 2 + nn] = __builtin_amdgcn_mfma_f32_16x16x32_bf16(
            aF[QM * 4 + mm][s], bF[nn][s], acc[QM * 4 + mm][QN * 2 + nn], 0, 0, 0);
}

// Stage macros: slot (q,j) at tile-offset TB (relative to running offA/offB which
// hold base + group*128). Global source pre-swizzled; LDS dest linear (rule #21).
#define STA(QQ, JJ, BUF, TB)                                                      \
  gload_lds16(Ab + (offA + (unsigned)((TB) * 128) +                               \
                    (unsigned)(((QQ) * 128 + (JJ) * 64) * ldA2)),                 \
              lds + (BUF) * 65536 + (QQ) * 16384 + (JJ) * 8192 + ldsbase)
#define STB(QQ, JJ, BUF, TB)                                                      \
  gload_lds16(Bb + (offB + (unsigned)((TB) * 128) +                               \
                    (unsigned)(((QQ) * 128 + (JJ) * 64) * ldB2)),                 \
              lds + (BUF) * 65536 + 32768 + (QQ) * 16384 + (JJ) * 8192 + ldsbase)

// 256x256 tile, BK=64, 8 waves (2M x 4N), 8-phase pipelined K-loop,
// double-buffered 128KB LDS, counted vmcnt(6), setprio around MFMA clusters.
__device__ __forceinline__ void gemm_core(
    const char* __restrict__ Ab, const char* __restrict__ Bb,
    long bm0, long bn0, int ldA2, int ldB2, int KT, char* lds,
    f32x4 (&acc)[8][4]) {
  int tid = threadIdx.x;
  int w = tid >> 6, lane = tid & 63;
  int wr = w >> 2, wc = w & 3;
  int r = lane & 15, g = lane >> 4;
  int ldsbase = w * 1024;
  int P0 = w * 1024 + lane * 16;
  int L0 = SWZ(P0);
  unsigned offA = (unsigned)((bm0 + (L0 >> 7)) * (long)ldA2) + (L0 & 127);
  unsigned offB = (unsigned)((bn0 + (L0 >> 7)) * (long)ldB2) + (L0 & 127);

  // prologue: tile0 q0..q3 (buf0), tile1 q0..q2 (buf1) = 7 halves, 14 loads
  STA(0, 0, 0, 0); STA(0, 1, 0, 0); STA(1, 0, 0, 0); STA(1, 1, 0, 0);
  STB(0, 0, 0, 0); STB(0, 1, 0, 0); STB(1, 0, 0, 0); STB(1, 1, 0, 0);
  STA(0, 0, 1, 1); STA(0, 1, 1, 1); STA(1, 0, 1, 1); STA(1, 1, 1, 1);
  STB(0, 0, 1, 1); STB(0, 1, 1, 1);
  asm volatile("s_waitcnt vmcnt(6)" ::: "memory");
  __builtin_amdgcn_s_barrier();

  bf16x8 aF[8][2], bF[2][2];
  int niter = KT >> 1;
  for (int it = 0; it < niter; ++it) {
    bool last = (it == niter - 1);
#pragma unroll
    for (int c = 0; c < 2; ++c) {
      int t = 2 * it + c;
      bool en0 = (t + 1 < KT);
      bool en1 = (t + 2 < KT);
      const char* tA = lds + c * 65536;
      const char* tB = tA + 32768;
      // ---- ph0: all A frags + B quad0; stage q3 of tile t+1 (buf 1-c) ----
      readA(tA, wr, r, g, aF);
      readB(tB, wc, 0, r, g, bF);
      if (en0) { STB(1, 0, 1 - c, 1); STB(1, 1, 1 - c, 1); }
      __builtin_amdgcn_s_barrier();
      asm volatile("s_waitcnt lgkmcnt(0)" ::: "memory");
      __builtin_amdgcn_s_setprio(1);
      mfma_quad<0, 0>(acc, aF, bF);
      __builtin_amdgcn_s_setprio(0);
      __builtin_amdgcn_s_barrier();
      // ---- ph1: stage q0 of tile t+2 (buf c) ----
      if (en1) { STA(0, 0, c, 2); STA(0, 1, c, 2); }
      __builtin_amdgcn_s_barrier();
      __builtin_amdgcn_s_setprio(1);
      mfma_quad<1, 0>(acc, aF, bF);
      __builtin_amdgcn_s_setprio(0);
      __builtin_amdgcn_s_barrier();
      // ---- ph2: B quad1; stage q1 of tile t+2 ----
      readB(tB, wc, 1, r, g, bF);
      if (en1) { STA(1, 0, c, 2); STA(1, 1, c, 2); }
      __builtin_amdgcn_s_barrier();
      asm volatile("s_waitcnt lgkmcnt(0)" ::: "memory");
      __builtin_amdgcn_s_setprio(1);
      mfma_quad<1, 1>(acc, aF, bF);
      __builtin_amdgcn_s_setprio(0);
      __builtin_amdgcn_s_barrier();
      // ---- ph3: stage q2 of tile t+2; K-tile boundary vmcnt ----
      if (en1) { STB(0, 0, c, 2); STB(0, 1, c, 2); }
      __builtin_amdgcn_s_barrier();
      __builtin_amdgcn_s_setprio(1);
      mfma_quad<0, 1>(acc, aF, bF);
      __builtin_amdgcn_s_setprio(0);
      if (!last)
        asm volatile("s_waitcnt vmcnt(6)" ::: "memory");
      else if (c == 0)
        asm volatile("s_waitcnt vmcnt(0)" ::: "memory");
      __builtin_amdgcn_s_barrier();
      offA += 128;
      offB += 128;
    }
  }
}

// ---------------- GEMM1: qkv = x @ W^T + b (bf16 out) ----------------
__global__ __launch_bounds__(512, 2) void gemm1_qkv(
    const unsigned short* __restrict__ A, const unsigned short* __restrict__ Bm,
    const float* __restrict__ bias, unsigned short* __restrict__ C) {
  extern __shared__ char smem[];
  int bid = blockIdx.x;
  int s = (bid & 7) * 96 + (bid >> 3);  // XCD swizzle, 768 % 8 == 0
  long bm0 = (long)(s / 12) * 256;
  long bn0 = (long)(s % 12) * 256;
  f32x4 acc[8][4] = {};
  gemm_core((const char*)A, (const char*)Bm, bm0, bn0, 2048, 2048, 16, smem, acc);
  int tid = threadIdx.x, w = tid >> 6, lane = tid & 63;
  int wr = w >> 2, wc = w & 3, r = lane & 15, g = lane >> 4;
#pragma unroll
  for (int n = 0; n < 4; ++n) {
    long col = bn0 + wc * 64 + n * 16 + r;
    float bv = bias[col];
#pragma unroll
    for (int m = 0; m < 8; ++m)
#pragma unroll
      for (int j = 0; j < 4; ++j) {
        long row = bm0 + wr * 128 + m * 16 + g * 4 + j;
        C[row * 3072 + col] = f2b(acc[m][n][j] + bv);
      }
  }
}

// ------------- GEMM2: scores = tril(q @ k^T) * inv_scale (bf16) -------------
__global__ __launch_bounds__(512, 2) void gemm2_scores(
    const unsigned short* __restrict__ qkv, unsigned short* __restrict__ scores,
    float inv_scale) {
  extern __shared__ char smem[];
  int bj = blockIdx.x, bi = blockIdx.y, b = blockIdx.z;
  if (bj > bi) return;
  const unsigned short* A = qkv + (long)b * 2048 * 3072;
  const unsigned short* Bm = A + 1024;
  long bm0 = (long)bi * 256, bn0 = (long)bj * 256;
  f32x4 acc[8][4] = {};
  gemm_core((const char*)A, (const char*)Bm, bm0, bn0, 6144, 6144, 16, smem, acc);
  unsigned short* S = scores + (long)b * 2048 * 2048;
  int tid = threadIdx.x, w = tid >> 6, lane = tid & 63;
  int wr = w >> 2, wc = w & 3, r = lane & 15, g = lane >> 4;
#pragma unroll
  for (int n = 0; n < 4; ++n) {
    long col = bn0 + wc * 64 + n * 16 + r;
#pragma unroll
    for (int m = 0; m < 8; ++m)
#pragma unroll
      for (int j = 0; j < 4; ++j) {
        long row = bm0 + wr * 128 + m * 16 + g * 4 + j;
        float v = acc[m][n][j] * inv_scale;
        if (col > row) v = 0.0f;
        S[row * 2048 + col] = f2b(v);
      }
  }
}

// ---------------- GEMM3: y = scores @ v (f32 out, causal K) ----------------
__global__ __launch_bounds__(512, 2) void gemm3_y(
    const unsigned short* __restrict__ scores, const unsigned short* __restrict__ vT,
    float* __restrict__ out) {
  extern __shared__ char smem[];
  int bn = blockIdx.x, bi = blockIdx.y, b = blockIdx.z;
  const unsigned short* A = scores + (long)b * 2048 * 2048;
  const unsigned short* Bm = vT + (long)b * 1024 * 2048;
  long bm0 = (long)bi * 256, bn0 = (long)bn * 256;
  f32x4 acc[8][4] = {};
  gemm_core((const char*)A, (const char*)Bm, bm0, bn0, 4096, 4096,
            (bi + 1) * 4, smem, acc);
  int tid = threadIdx.x, w = tid >> 6, lane = tid & 63;
  int wr = w >> 2, wc = w & 3, r = lane & 15, g = lane >> 4;
#pragma unroll
  for (int n = 0; n < 4; ++n) {
    long col = bn0 + wc * 64 + n * 16 + r;
#pragma unroll
    for (int m = 0; m < 8; ++m)
#pragma unroll
      for (int j = 0; j < 4; ++j) {
        long row = bm0 + wr * 128 + m * 16 + g * 4 + j;
        out[((long)b * 2048 + row) * 1024 + col] = acc[m][n][j];
      }
  }
}

// ---------------- f32 -> bf16 conversion ----------------
__global__ void cvt_f32_bf16(const float* __restrict__ in,
                             unsigned short* __restrict__ out, long n) {
  long i = ((long)blockIdx.x * blockDim.x + threadIdx.x) * 8;
  if (i + 8 > n) return;
  float4 a = *(const float4*)(in + i);
  float4 b = *(const float4*)(in + i + 4);
  bf16x8 o;
  o[0] = (short)f2b(a.x); o[1] = (short)f2b(a.y);
  o[2] = (short)f2b(a.z); o[3] = (short)f2b(a.w);
  o[4] = (short)f2b(b.x); o[5] = (short)f2b(b.y);
  o[6] = (short)f2b(b.z); o[7] = (short)f2b(b.w);
  *(bf16x8*)(out + i) = o;
}

// ---------------- transpose v: [b][t][d] -> [b][d][t] (bf16) ----------------
__global__ void transpose_v(const unsigned short* __restrict__ qkv,
                            unsigned short* __restrict__ vT) {
  __shared__ unsigned short tile[64][72];
  int t0 = blockIdx.x * 64, d0 = blockIdx.y * 64, b = blockIdx.z;
  int tid = threadIdx.x;
  int sub = tid & 15, grp = tid >> 4;
#pragma unroll
  for (int it = 0; it < 4; ++it) {
    int tt = it * 16 + grp;
    int dd = sub * 4;
    const unsigned short* src =
        qkv + ((long)(b * 2048 + t0 + tt)) * 3072 + 2048 + d0 + dd;
    *(us4*)&tile[tt][dd] = *(const us4*)src;
  }
  __syncthreads();
#pragma unroll
  for (int it = 0; it < 4; ++it) {
    int dd = it * 16 + grp;
    int ts = sub * 4;
    us4 o;
    o[0] = tile[ts + 0][dd];
    o[1] = tile[ts + 1][dd];
    o[2] = tile[ts + 2][dd];
    o[3] = tile[ts + 3][dd];
    *(us4*)(vT + ((long)b * 1024 + d0 + dd) * 2048 + t0 + ts) = o;
  }
}

// ---------------- LayerNorm (in-place on f32 out) ----------------
__global__ void ln_kernel(float* __restrict__ y, const float* __restrict__ wv,
                          const float* __restrict__ bv) {
  __shared__ float sm[4];
  long row = blockIdx.x;
  int tid = threadIdx.x;
  float4 v = *(const float4*)(y + row * 1024 + tid * 4);
  float s = v.x + v.y + v.z + v.w;
#pragma unroll
  for (int o = 32; o > 0; o >>= 1) s += __shfl_xor(s, o, 64);
  if ((tid & 63) == 0) sm[tid >> 6] = s;
  __syncthreads();
  float mu = (sm[0] + sm[1] + sm[2] + sm[3]) * (1.0f / 1024.0f);
  float dx = v.x - mu, dy = v.y - mu, dz = v.z - mu, dw = v.w - mu;
  float sq = dx * dx + dy * dy + dz * dz + dw * dw;
#pragma unroll
  for (int o = 32; o > 0; o >>= 1) sq += __shfl_xor(sq, o, 64);
  __syncthreads();
  if ((tid & 63) == 0) sm[tid >> 6] = sq;
  __syncthreads();
  float var = (sm[0] + sm[1] + sm[2] + sm[3]) * (1.0f / 1024.0f);
  float inv = rsqrtf(var + 1e-5f);
  float4 w4 = *(const float4*)(wv + tid * 4);
  float4 b4 = *(const float4*)(bv + tid * 4);
  float4 o4;
  o4.x = dx * inv * w4.x + b4.x;
  o4.y = dy * inv * w4.y + b4.y;
  o4.z = dz * inv * w4.z + b4.z;
  o4.w = dw * inv * w4.w + b4.w;
  *(float4*)(y + row * 1024 + tid * 4) = o4;
}

extern "C" void kernel_launch(void* const* d_in, const int* in_sizes, int n_in,
                              void* d_out, int out_size, void* d_ws, size_t ws_size,
                              hipStream_t stream) {
  const float* x = (const float*)d_in[0];
  const float* W = (const float*)d_in[1];
  const float* bq = (const float*)d_in[2];
  const float* lnw = (const float*)d_in[3];
  const float* lnb = (const float*)d_in[4];
  float* out = (float*)d_out;

  char* ws = (char*)d_ws;
  unsigned short* qkv = (unsigned short*)(ws);
  unsigned short* vT = (unsigned short*)(ws + 100663296L);
  unsigned short* sc = (unsigned short*)(ws + 134217728L);
  unsigned short* xb = (unsigned short*)(ws + 134217728L);
  unsigned short* Wb = (unsigned short*)(ws + 167772160L);

  const float inv_scale = 1.0f / sqrtf(1024.0f * 2048.0f);

  hipFuncSetAttribute((const void*)gemm1_qkv,
                      hipFuncAttributeMaxDynamicSharedMemorySize, 131072);
  hipFuncSetAttribute((const void*)gemm2_scores,
                      hipFuncAttributeMaxDynamicSharedMemorySize, 131072);
  hipFuncSetAttribute((const void*)gemm3_y,
                      hipFuncAttributeMaxDynamicSharedMemorySize, 131072);

  cvt_f32_bf16<<<8192, 256, 0, stream>>>(x, xb, 16384L * 1024);
  cvt_f32_bf16<<<1536, 256, 0, stream>>>(W, Wb, 3072L * 1024);
  gemm1_qkv<<<768, 512, 131072, stream>>>(xb, Wb, bq, qkv);
  transpose_v<<<dim3(32, 16, 8), 256, 0, stream>>>(qkv, vT);
  gemm2_scores<<<dim3(8, 8, 8), 512, 131072, stream>>>(qkv, sc, inv_scale);
  gemm3_y<<<dim3(4, 8, 8), 512, 131072, stream>>>(sc, vT, out);
  ln_kernel<<<16384, 256, 0, stream>>>(out, lnw, lnb);
}

// Round 6
// 650.878 us; speedup vs baseline: 1.3297x; 1.3045x over previous
//
#include <hip/hip_runtime.h>
#include <hip/hip_bf16.h>
#include <stdint.h>

typedef __attribute__((ext_vector_type(8))) short bf16x8;
typedef __attribute__((ext_vector_type(4))) float f32x4;
typedef __attribute__((ext_vector_type(4))) unsigned short us4;

// XOR swizzle within a 32KB [256 rows][128B] tile: flip byte-bits 4-6 by row&7.
#define SWZ(L) ((L) ^ ((((L) >> 7) & 7) << 4))

__device__ __forceinline__ unsigned short f2b(float f) {
  union { float f; unsigned u; } u;
  u.f = f;
  unsigned r = u.u + 0x7fffu + ((u.u >> 16) & 1u);
  return (unsigned short)(r >> 16);
}

__device__ __forceinline__ void gload_lds16(const void* g, void* lds) {
  __builtin_amdgcn_global_load_lds(
      (const __attribute__((address_space(1))) unsigned int*)(uintptr_t)g,
      (__attribute__((address_space(3))) unsigned int*)(uintptr_t)lds,
      16, 0, 0);
}

// ===================== 256^2 8-phase core (gemm1) =====================
__device__ __forceinline__ void readA(const char* tA, int wr, int r, int g,
                                      bf16x8 (&aF)[8][2]) {
#pragma unroll
  for (int m = 0; m < 8; ++m)
#pragma unroll
    for (int s = 0; s < 2; ++s) {
      int L = (wr * 128 + m * 16 + r) * 128 + s * 64 + g * 16;
      aF[m][s] = *(const bf16x8*)(tA + SWZ(L));
    }
}

__device__ __forceinline__ void readB(const char* tB, int wc, int qn, int r, int g,
                                      bf16x8 (&bF)[2][2]) {
#pragma unroll
  for (int n = 0; n < 2; ++n)
#pragma unroll
    for (int s = 0; s < 2; ++s) {
      int L = (wc * 64 + (qn * 2 + n) * 16 + r) * 128 + s * 64 + g * 16;
      bF[n][s] = *(const bf16x8*)(tB + SWZ(L));
    }
}

template <int QM, int QN>
__device__ __forceinline__ void mfma_quad(f32x4 (&acc)[8][4], bf16x8 (&aF)[8][2],
                                          bf16x8 (&bF)[2][2]) {
#pragma unroll
  for (int s = 0; s < 2; ++s)
#pragma unroll
    for (int mm = 0; mm < 4; ++mm)
#pragma unroll
      for (int nn = 0; nn < 2; ++nn)
        acc[QM * 4 + mm][QN * 2 + nn] = __builtin_amdgcn_mfma_f32_16x16x32_bf16(
            aF[QM * 4 + mm][s], bF[nn][s], acc[QM * 4 + mm][QN * 2 + nn], 0, 0, 0);
}

#define STA(QQ, JJ, BUF, TB)                                                      \
  gload_lds16(Ab + (offA + (unsigned)((TB) * 128) +                               \
                    (unsigned)(((QQ) * 128 + (JJ) * 64) * ldA2)),                 \
              lds + (BUF) * 65536 + (QQ) * 16384 + (JJ) * 8192 + ldsbase)
#define STB(QQ, JJ, BUF, TB)                                                      \
  gload_lds16(Bb + (offB + (unsigned)((TB) * 128) +                               \
                    (unsigned)(((QQ) * 128 + (JJ) * 64) * ldB2)),                 \
              lds + (BUF) * 65536 + 32768 + (QQ) * 16384 + (JJ) * 8192 + ldsbase)

__device__ __forceinline__ void gemm_core(
    const char* __restrict__ Ab, const char* __restrict__ Bb,
    long bm0, long bn0, int ldA2, int ldB2, int KT, char* lds,
    f32x4 (&acc)[8][4]) {
  int tid = threadIdx.x;
  int w = tid >> 6, lane = tid & 63;
  int wr = w >> 2, wc = w & 3;
  int r = lane & 15, g = lane >> 4;
  int ldsbase = w * 1024;
  int P0 = w * 1024 + lane * 16;
  int L0 = SWZ(P0);
  unsigned offA = (unsigned)((bm0 + (L0 >> 7)) * (long)ldA2) + (L0 & 127);
  unsigned offB = (unsigned)((bn0 + (L0 >> 7)) * (long)ldB2) + (L0 & 127);

  STA(0, 0, 0, 0); STA(0, 1, 0, 0); STA(1, 0, 0, 0); STA(1, 1, 0, 0);
  STB(0, 0, 0, 0); STB(0, 1, 0, 0); STB(1, 0, 0, 0); STB(1, 1, 0, 0);
  STA(0, 0, 1, 1); STA(0, 1, 1, 1); STA(1, 0, 1, 1); STA(1, 1, 1, 1);
  STB(0, 0, 1, 1); STB(0, 1, 1, 1);
  asm volatile("s_waitcnt vmcnt(6)" ::: "memory");
  __builtin_amdgcn_s_barrier();

  bf16x8 aF[8][2], bF[2][2];
  int niter = KT >> 1;
  for (int it = 0; it < niter; ++it) {
    bool last = (it == niter - 1);
#pragma unroll
    for (int c = 0; c < 2; ++c) {
      int t = 2 * it + c;
      bool en0 = (t + 1 < KT);
      bool en1 = (t + 2 < KT);
      const char* tA = lds + c * 65536;
      const char* tB = tA + 32768;
      readA(tA, wr, r, g, aF);
      readB(tB, wc, 0, r, g, bF);
      if (en0) { STB(1, 0, 1 - c, 1); STB(1, 1, 1 - c, 1); }
      __builtin_amdgcn_s_barrier();
      asm volatile("s_waitcnt lgkmcnt(0)" ::: "memory");
      __builtin_amdgcn_s_setprio(1);
      mfma_quad<0, 0>(acc, aF, bF);
      __builtin_amdgcn_s_setprio(0);
      __builtin_amdgcn_s_barrier();
      if (en1) { STA(0, 0, c, 2); STA(0, 1, c, 2); }
      __builtin_amdgcn_s_barrier();
      __builtin_amdgcn_s_setprio(1);
      mfma_quad<1, 0>(acc, aF, bF);
      __builtin_amdgcn_s_setprio(0);
      __builtin_amdgcn_s_barrier();
      readB(tB, wc, 1, r, g, bF);
      if (en1) { STA(1, 0, c, 2); STA(1, 1, c, 2); }
      __builtin_amdgcn_s_barrier();
      asm volatile("s_waitcnt lgkmcnt(0)" ::: "memory");
      __builtin_amdgcn_s_setprio(1);
      mfma_quad<1, 1>(acc, aF, bF);
      __builtin_amdgcn_s_setprio(0);
      __builtin_amdgcn_s_barrier();
      if (en1) { STB(0, 0, c, 2); STB(0, 1, c, 2); }
      __builtin_amdgcn_s_barrier();
      __builtin_amdgcn_s_setprio(1);
      mfma_quad<0, 1>(acc, aF, bF);
      __builtin_amdgcn_s_setprio(0);
      if (!last)
        asm volatile("s_waitcnt vmcnt(6)" ::: "memory");
      else if (c == 0)
        asm volatile("s_waitcnt vmcnt(0)" ::: "memory");
      __builtin_amdgcn_s_barrier();
      offA += 128;
      offB += 128;
    }
  }
}

// gemm1: qkv projection, deinterleaved outputs q/k/v, natural grid (bn fastest).
__global__ __launch_bounds__(512, 2) void gemm1_qkv(
    const unsigned short* __restrict__ A, const unsigned short* __restrict__ Bm,
    const float* __restrict__ bias, unsigned short* __restrict__ qb,
    unsigned short* __restrict__ kb, unsigned short* __restrict__ vb) {
  extern __shared__ char smem[];
  long bm0 = (long)blockIdx.y * 256;
  long bn0 = (long)blockIdx.x * 256;
  f32x4 acc[8][4] = {};
  gemm_core((const char*)A, (const char*)Bm, bm0, bn0, 2048, 2048, 16, smem, acc);
  int tid = threadIdx.x, w = tid >> 6, lane = tid & 63;
  int wr = w >> 2, wc = w & 3, r = lane & 15, g = lane >> 4;
  int part = blockIdx.x >> 2;  // 0=q 1=k 2=v (256-col tiles never straddle)
  unsigned short* O = (part == 0) ? qb : (part == 1) ? kb : vb;
  long cl0 = (long)(blockIdx.x & 3) * 256;
#pragma unroll
  for (int n = 0; n < 4; ++n) {
    long cc = wc * 64 + n * 16 + r;
    float bv = bias[bn0 + cc];
#pragma unroll
    for (int m = 0; m < 8; ++m)
#pragma unroll
      for (int j = 0; j < 4; ++j) {
        long row = bm0 + wr * 128 + m * 16 + g * 4 + j;
        O[row * 1024 + cl0 + cc] = f2b(acc[m][n][j] + bv);
      }
  }
}

// ===================== 128^2 m97 structure (gemm2/gemm3) =====================
#define TILE_M 128
#define TILE_K 32

__device__ __forceinline__ void stage_tile(const unsigned short* __restrict__ g,
                                           long ld, long row0,
                                           unsigned short* lds, int tid) {
  int w = tid >> 6, lane = tid & 63;
#pragma unroll
  for (int j = 0; j < 2; ++j) {
    int o = ((w * 2 + j) << 10) + lane * 16;
    int row = o >> 6;
    int col = (o & 63) >> 1;
    const unsigned short* gp = g + (row0 + row) * ld + col;
    gload_lds16(gp, (char*)lds + ((w * 2 + j) << 10));
  }
}

// gemm2: scores = tril(q k^T) * inv_scale; grid.x = 136 lower-tri tiles.
__global__ __launch_bounds__(256, 2) void gemm2_scores(
    const unsigned short* __restrict__ qm, const unsigned short* __restrict__ km,
    unsigned short* __restrict__ scores, float inv_scale) {
  __shared__ unsigned short lsA[TILE_M * TILE_K];
  __shared__ unsigned short lsB[TILE_M * TILE_K];
  int p = 135 - blockIdx.x;  // heavy-first
  int bi = 0, base = 0;
  while (p >= base + bi + 1) { base += bi + 1; ++bi; }
  int bj = p - base;
  int b = blockIdx.y;
  int tid = threadIdx.x;
  int lane = tid & 63, w = tid >> 6;
  int wr = w >> 1, wc = w & 1;
  long bm0 = (long)bi * TILE_M;
  long bn0 = (long)bj * TILE_M;
  const unsigned short* A = qm + (long)b * 2048 * 1024;
  const unsigned short* Bm = km + (long)b * 2048 * 1024;
  f32x4 acc[4][4] = {};
  int r = lane & 15, g = lane >> 4;
  for (int kt = 0; kt < 1024 / TILE_K; ++kt) {
    long k0 = (long)kt * TILE_K;
    stage_tile(A + k0, 1024, bm0, lsA, tid);
    stage_tile(Bm + k0, 1024, bn0, lsB, tid);
    __syncthreads();
    bf16x8 aF[4], bF[4];
#pragma unroll
    for (int m = 0; m < 4; ++m)
      aF[m] = *(const bf16x8*)(lsA + (wr * 64 + m * 16 + r) * 32 + g * 8);
#pragma unroll
    for (int n = 0; n < 4; ++n)
      bF[n] = *(const bf16x8*)(lsB + (wc * 64 + n * 16 + r) * 32 + g * 8);
#pragma unroll
    for (int m = 0; m < 4; ++m)
#pragma unroll
      for (int n = 0; n < 4; ++n)
        acc[m][n] = __builtin_amdgcn_mfma_f32_16x16x32_bf16(aF[m], bF[n], acc[m][n], 0, 0, 0);
    __syncthreads();
  }
  unsigned short* S = scores + (long)b * 2048 * 2048;
#pragma unroll
  for (int n = 0; n < 4; ++n) {
    long col = bn0 + wc * 64 + n * 16 + r;
#pragma unroll
    for (int m = 0; m < 4; ++m)
#pragma unroll
      for (int j = 0; j < 4; ++j) {
        long row = bm0 + wr * 64 + m * 16 + g * 4 + j;
        float v = acc[m][n][j] * inv_scale;
        if (col > row) v = 0.0f;
        S[row * 2048 + col] = f2b(v);
      }
  }
}

// gemm3: y = scores @ v (f32 out), causal K, heavy-first bi.
__global__ __launch_bounds__(256, 2) void gemm3_y(
    const unsigned short* __restrict__ scores, const unsigned short* __restrict__ vT,
    float* __restrict__ out) {
  __shared__ unsigned short lsA[TILE_M * TILE_K];
  __shared__ unsigned short lsB[TILE_M * TILE_K];
  int bn = blockIdx.x, bi = 15 - blockIdx.y, b = blockIdx.z;
  int tid = threadIdx.x;
  int lane = tid & 63, w = tid >> 6;
  int wr = w >> 1, wc = w & 1;
  long bm0 = (long)bi * TILE_M;
  long bn0 = (long)bn * TILE_M;
  const unsigned short* A = scores + (long)b * 2048 * 2048;
  const unsigned short* Bm = vT + (long)b * 1024 * 2048;
  f32x4 acc[4][4] = {};
  int r = lane & 15, g = lane >> 4;
  int KT = (bi + 1) * (TILE_M / TILE_K);
  for (int kt = 0; kt < KT; ++kt) {
    long k0 = (long)kt * TILE_K;
    stage_tile(A + k0, 2048, bm0, lsA, tid);
    stage_tile(Bm + k0, 2048, bn0, lsB, tid);
    __syncthreads();
    bf16x8 aF[4], bF[4];
#pragma unroll
    for (int m = 0; m < 4; ++m)
      aF[m] = *(const bf16x8*)(lsA + (wr * 64 + m * 16 + r) * 32 + g * 8);
#pragma unroll
    for (int n = 0; n < 4; ++n)
      bF[n] = *(const bf16x8*)(lsB + (wc * 64 + n * 16 + r) * 32 + g * 8);
#pragma unroll
    for (int m = 0; m < 4; ++m)
#pragma unroll
      for (int n = 0; n < 4; ++n)
        acc[m][n] = __builtin_amdgcn_mfma_f32_16x16x32_bf16(aF[m], bF[n], acc[m][n], 0, 0, 0);
    __syncthreads();
  }
#pragma unroll
  for (int n = 0; n < 4; ++n) {
    long col = bn0 + wc * 64 + n * 16 + r;
#pragma unroll
    for (int m = 0; m < 4; ++m)
#pragma unroll
      for (int j = 0; j < 4; ++j) {
        long row = bm0 + wr * 64 + m * 16 + g * 4 + j;
        out[((long)b * 2048 + row) * 1024 + col] = acc[m][n][j];
      }
  }
}

// ---------------- f32 -> bf16 conversion ----------------
__global__ void cvt_f32_bf16(const float* __restrict__ in,
                             unsigned short* __restrict__ out, long n) {
  long i = ((long)blockIdx.x * blockDim.x + threadIdx.x) * 8;
  if (i + 8 > n) return;
  float4 a = *(const float4*)(in + i);
  float4 b = *(const float4*)(in + i + 4);
  bf16x8 o;
  o[0] = (short)f2b(a.x); o[1] = (short)f2b(a.y);
  o[2] = (short)f2b(a.z); o[3] = (short)f2b(a.w);
  o[4] = (short)f2b(b.x); o[5] = (short)f2b(b.y);
  o[6] = (short)f2b(b.z); o[7] = (short)f2b(b.w);
  *(bf16x8*)(out + i) = o;
}

// ---------------- transpose v: [b][t][d] -> [b][d][t] (bf16) ----------------
__global__ void transpose_v(const unsigned short* __restrict__ vm,
                            unsigned short* __restrict__ vT) {
  __shared__ unsigned short tile[64][72];
  int t0 = blockIdx.x * 64, d0 = blockIdx.y * 64, b = blockIdx.z;
  int tid = threadIdx.x;
  int sub = tid & 15, grp = tid >> 4;
#pragma unroll
  for (int it = 0; it < 4; ++it) {
    int tt = it * 16 + grp;
    int dd = sub * 4;
    const unsigned short* src =
        vm + ((long)(b * 2048 + t0 + tt)) * 1024 + d0 + dd;
    *(us4*)&tile[tt][dd] = *(const us4*)src;
  }
  __syncthreads();
#pragma unroll
  for (int it = 0; it < 4; ++it) {
    int dd = it * 16 + grp;
    int ts = sub * 4;
    us4 o;
    o[0] = tile[ts + 0][dd];
    o[1] = tile[ts + 1][dd];
    o[2] = tile[ts + 2][dd];
    o[3] = tile[ts + 3][dd];
    *(us4*)(vT + ((long)b * 1024 + d0 + dd) * 2048 + t0 + ts) = o;
  }
}

// ---------------- LayerNorm (in-place on f32 out) ----------------
__global__ void ln_kernel(float* __restrict__ y, const float* __restrict__ wv,
                          const float* __restrict__ bv) {
  __shared__ float sm[4];
  long row = blockIdx.x;
  int tid = threadIdx.x;
  float4 v = *(const float4*)(y + row * 1024 + tid * 4);
  float s = v.x + v.y + v.z + v.w;
#pragma unroll
  for (int o = 32; o > 0; o >>= 1) s += __shfl_xor(s, o, 64);
  if ((tid & 63) == 0) sm[tid >> 6] = s;
  __syncthreads();
  float mu = (sm[0] + sm[1] + sm[2] + sm[3]) * (1.0f / 1024.0f);
  float dx = v.x - mu, dy = v.y - mu, dz = v.z - mu, dw = v.w - mu;
  float sq = dx * dx + dy * dy + dz * dz + dw * dw;
#pragma unroll
  for (int o = 32; o > 0; o >>= 1) sq += __shfl_xor(sq, o, 64);
  __syncthreads();
  if ((tid & 63) == 0) sm[tid >> 6] = sq;
  __syncthreads();
  float var = (sm[0] + sm[1] + sm[2] + sm[3]) * (1.0f / 1024.0f);
  float inv = rsqrtf(var + 1e-5f);
  float4 w4 = *(const float4*)(wv + tid * 4);
  float4 b4 = *(const float4*)(bv + tid * 4);
  float4 o4;
  o4.x = dx * inv * w4.x + b4.x;
  o4.y = dy * inv * w4.y + b4.y;
  o4.z = dz * inv * w4.z + b4.z;
  o4.w = dw * inv * w4.w + b4.w;
  *(float4*)(y + row * 1024 + tid * 4) = o4;
}

extern "C" void kernel_launch(void* const* d_in, const int* in_sizes, int n_in,
                              void* d_out, int out_size, void* d_ws, size_t ws_size,
                              hipStream_t stream) {
  const float* x = (const float*)d_in[0];
  const float* W = (const float*)d_in[1];
  const float* bq = (const float*)d_in[2];
  const float* lnw = (const float*)d_in[3];
  const float* lnb = (const float*)d_in[4];
  float* out = (float*)d_out;

  char* ws = (char*)d_ws;
  // q[0,32M) k[32M,64M) v[64M,96M) vT[96M,128M) {xb[128M,160M) Wb[160M,166M)}
  // scores[128M,192M) aliases xb/Wb (dead after gemm1). Total 192 MiB.
  unsigned short* qb = (unsigned short*)(ws);
  unsigned short* kb = (unsigned short*)(ws + 33554432L);
  unsigned short* vb = (unsigned short*)(ws + 67108864L);
  unsigned short* vT = (unsigned short*)(ws + 100663296L);
  unsigned short* xb = (unsigned short*)(ws + 134217728L);
  unsigned short* Wb = (unsigned short*)(ws + 167772160L);
  unsigned short* sc = (unsigned short*)(ws + 134217728L);

  const float inv_scale = 1.0f / sqrtf(1024.0f * 2048.0f);

  hipFuncSetAttribute((const void*)gemm1_qkv,
                      hipFuncAttributeMaxDynamicSharedMemorySize, 131072);

  cvt_f32_bf16<<<8192, 256, 0, stream>>>(x, xb, 16384L * 1024);
  cvt_f32_bf16<<<1536, 256, 0, stream>>>(W, Wb, 3072L * 1024);
  gemm1_qkv<<<dim3(12, 64), 512, 131072, stream>>>(xb, Wb, bq, qb, kb, vb);
  transpose_v<<<dim3(32, 16, 8), 256, 0, stream>>>(vb, vT);
  gemm2_scores<<<dim3(136, 8), 256, 0, stream>>>(qb, kb, sc, inv_scale);
  gemm3_y<<<dim3(8, 16, 8), 256, 0, stream>>>(sc, vT, out);
  ln_kernel<<<16384, 256, 0, stream>>>(out, lnw, lnb);
}

// Round 7
// 448.612 us; speedup vs baseline: 1.9292x; 1.4509x over previous
//
#include <hip/hip_runtime.h>
#include <hip/hip_bf16.h>
#include <stdint.h>

typedef __attribute__((ext_vector_type(8))) short bf16x8;
typedef __attribute__((ext_vector_type(4))) float f32x4;
typedef __attribute__((ext_vector_type(4))) unsigned short us4;

__device__ __forceinline__ unsigned short f2b(float f) {
  union { float f; unsigned u; } u;
  u.f = f;
  unsigned r = u.u + 0x7fffu + ((u.u >> 16) & 1u);
  return (unsigned short)(r >> 16);
}

__device__ __forceinline__ void gload_lds16(const void* g, void* lds) {
  __builtin_amdgcn_global_load_lds(
      (const __attribute__((address_space(1))) unsigned int*)(uintptr_t)g,
      (__attribute__((address_space(3))) unsigned int*)(uintptr_t)lds,
      16, 0, 0);
}

// ===================== 128^2 m97 structure (all GEMMs) =====================
#define TILE_M 128
#define TILE_K 32

__device__ __forceinline__ void stage_tile(const unsigned short* __restrict__ g,
                                           long ld, long row0,
                                           unsigned short* lds, int tid) {
  int w = tid >> 6, lane = tid & 63;
#pragma unroll
  for (int j = 0; j < 2; ++j) {
    int o = ((w * 2 + j) << 10) + lane * 16;
    int row = o >> 6;
    int col = (o & 63) >> 1;
    const unsigned short* gp = g + (row0 + row) * ld + col;
    gload_lds16(gp, (char*)lds + ((w * 2 + j) << 10));
  }
}

// gemm1: qkv = x @ W^T + b, deinterleaved q/k/v outputs (m97 structure, R1-verified).
__global__ __launch_bounds__(256, 2) void gemm1_qkv(
    const unsigned short* __restrict__ A,   // x bf16 [16384][1024]
    const unsigned short* __restrict__ Bm,  // W bf16 [3072][1024]
    const float* __restrict__ bias,         // [3072] f32
    unsigned short* __restrict__ qb, unsigned short* __restrict__ kb,
    unsigned short* __restrict__ vb) {
  __shared__ unsigned short lsA[TILE_M * TILE_K];
  __shared__ unsigned short lsB[TILE_M * TILE_K];
  int tid = threadIdx.x;
  int lane = tid & 63, w = tid >> 6;
  int wr = w >> 1, wc = w & 1;
  long bm0 = (long)blockIdx.y * TILE_M;
  long bn0 = (long)blockIdx.x * TILE_M;
  f32x4 acc[4][4] = {};
  int r = lane & 15, g = lane >> 4;
  for (int kt = 0; kt < 1024 / TILE_K; ++kt) {
    long k0 = (long)kt * TILE_K;
    stage_tile(A + k0, 1024, bm0, lsA, tid);
    stage_tile(Bm + k0, 1024, bn0, lsB, tid);
    __syncthreads();
    bf16x8 aF[4], bF[4];
#pragma unroll
    for (int m = 0; m < 4; ++m)
      aF[m] = *(const bf16x8*)(lsA + (wr * 64 + m * 16 + r) * 32 + g * 8);
#pragma unroll
    for (int n = 0; n < 4; ++n)
      bF[n] = *(const bf16x8*)(lsB + (wc * 64 + n * 16 + r) * 32 + g * 8);
#pragma unroll
    for (int m = 0; m < 4; ++m)
#pragma unroll
      for (int n = 0; n < 4; ++n)
        acc[m][n] = __builtin_amdgcn_mfma_f32_16x16x32_bf16(aF[m], bF[n], acc[m][n], 0, 0, 0);
    __syncthreads();
  }
  // epilogue: part = bn/8 selects q/k/v (128-col tiles never straddle parts)
  int part = blockIdx.x >> 3;
  unsigned short* O = (part == 0) ? qb : (part == 1) ? kb : vb;
  long cl0 = (long)(blockIdx.x & 7) * 128;
#pragma unroll
  for (int n = 0; n < 4; ++n) {
    long cc = wc * 64 + n * 16 + r;
    float bv = bias[bn0 + cc];
#pragma unroll
    for (int m = 0; m < 4; ++m)
#pragma unroll
      for (int j = 0; j < 4; ++j) {
        long row = bm0 + wr * 64 + m * 16 + g * 4 + j;
        O[row * 1024 + cl0 + cc] = f2b(acc[m][n][j] + bv);
      }
  }
}

// gemm2: scores = tril(q k^T) * inv_scale; grid.x = 136 lower-tri tiles.
__global__ __launch_bounds__(256, 2) void gemm2_scores(
    const unsigned short* __restrict__ qm, const unsigned short* __restrict__ km,
    unsigned short* __restrict__ scores, float inv_scale) {
  __shared__ unsigned short lsA[TILE_M * TILE_K];
  __shared__ unsigned short lsB[TILE_M * TILE_K];
  int p = 135 - blockIdx.x;  // heavy-first
  int bi = 0, base = 0;
  while (p >= base + bi + 1) { base += bi + 1; ++bi; }
  int bj = p - base;
  int b = blockIdx.y;
  int tid = threadIdx.x;
  int lane = tid & 63, w = tid >> 6;
  int wr = w >> 1, wc = w & 1;
  long bm0 = (long)bi * TILE_M;
  long bn0 = (long)bj * TILE_M;
  const unsigned short* A = qm + (long)b * 2048 * 1024;
  const unsigned short* Bm = km + (long)b * 2048 * 1024;
  f32x4 acc[4][4] = {};
  int r = lane & 15, g = lane >> 4;
  for (int kt = 0; kt < 1024 / TILE_K; ++kt) {
    long k0 = (long)kt * TILE_K;
    stage_tile(A + k0, 1024, bm0, lsA, tid);
    stage_tile(Bm + k0, 1024, bn0, lsB, tid);
    __syncthreads();
    bf16x8 aF[4], bF[4];
#pragma unroll
    for (int m = 0; m < 4; ++m)
      aF[m] = *(const bf16x8*)(lsA + (wr * 64 + m * 16 + r) * 32 + g * 8);
#pragma unroll
    for (int n = 0; n < 4; ++n)
      bF[n] = *(const bf16x8*)(lsB + (wc * 64 + n * 16 + r) * 32 + g * 8);
#pragma unroll
    for (int m = 0; m < 4; ++m)
#pragma unroll
      for (int n = 0; n < 4; ++n)
        acc[m][n] = __builtin_amdgcn_mfma_f32_16x16x32_bf16(aF[m], bF[n], acc[m][n], 0, 0, 0);
    __syncthreads();
  }
  unsigned short* S = scores + (long)b * 2048 * 2048;
#pragma unroll
  for (int n = 0; n < 4; ++n) {
    long col = bn0 + wc * 64 + n * 16 + r;
#pragma unroll
    for (int m = 0; m < 4; ++m)
#pragma unroll
      for (int j = 0; j < 4; ++j) {
        long row = bm0 + wr * 64 + m * 16 + g * 4 + j;
        float v = acc[m][n][j] * inv_scale;
        if (col > row) v = 0.0f;
        S[row * 2048 + col] = f2b(v);
      }
  }
}

// gemm3: y = scores @ v (f32 out), causal K, heavy-first bi.
__global__ __launch_bounds__(256, 2) void gemm3_y(
    const unsigned short* __restrict__ scores, const unsigned short* __restrict__ vT,
    float* __restrict__ out) {
  __shared__ unsigned short lsA[TILE_M * TILE_K];
  __shared__ unsigned short lsB[TILE_M * TILE_K];
  int bn = blockIdx.x, bi = 15 - blockIdx.y, b = blockIdx.z;
  int tid = threadIdx.x;
  int lane = tid & 63, w = tid >> 6;
  int wr = w >> 1, wc = w & 1;
  long bm0 = (long)bi * TILE_M;
  long bn0 = (long)bn * TILE_M;
  const unsigned short* A = scores + (long)b * 2048 * 2048;
  const unsigned short* Bm = vT + (long)b * 1024 * 2048;
  f32x4 acc[4][4] = {};
  int r = lane & 15, g = lane >> 4;
  int KT = (bi + 1) * (TILE_M / TILE_K);
  for (int kt = 0; kt < KT; ++kt) {
    long k0 = (long)kt * TILE_K;
    stage_tile(A + k0, 2048, bm0, lsA, tid);
    stage_tile(Bm + k0, 2048, bn0, lsB, tid);
    __syncthreads();
    bf16x8 aF[4], bF[4];
#pragma unroll
    for (int m = 0; m < 4; ++m)
      aF[m] = *(const bf16x8*)(lsA + (wr * 64 + m * 16 + r) * 32 + g * 8);
#pragma unroll
    for (int n = 0; n < 4; ++n)
      bF[n] = *(const bf16x8*)(lsB + (wc * 64 + n * 16 + r) * 32 + g * 8);
#pragma unroll
    for (int m = 0; m < 4; ++m)
#pragma unroll
      for (int n = 0; n < 4; ++n)
        acc[m][n] = __builtin_amdgcn_mfma_f32_16x16x32_bf16(aF[m], bF[n], acc[m][n], 0, 0, 0);
    __syncthreads();
  }
#pragma unroll
  for (int n = 0; n < 4; ++n) {
    long col = bn0 + wc * 64 + n * 16 + r;
#pragma unroll
    for (int m = 0; m < 4; ++m)
#pragma unroll
      for (int j = 0; j < 4; ++j) {
        long row = bm0 + wr * 64 + m * 16 + g * 4 + j;
        out[((long)b * 2048 + row) * 1024 + col] = acc[m][n][j];
      }
  }
}

// ---------------- f32 -> bf16 conversion ----------------
__global__ void cvt_f32_bf16(const float* __restrict__ in,
                             unsigned short* __restrict__ out, long n) {
  long i = ((long)blockIdx.x * blockDim.x + threadIdx.x) * 8;
  if (i + 8 > n) return;
  float4 a = *(const float4*)(in + i);
  float4 b = *(const float4*)(in + i + 4);
  bf16x8 o;
  o[0] = (short)f2b(a.x); o[1] = (short)f2b(a.y);
  o[2] = (short)f2b(a.z); o[3] = (short)f2b(a.w);
  o[4] = (short)f2b(b.x); o[5] = (short)f2b(b.y);
  o[6] = (short)f2b(b.z); o[7] = (short)f2b(b.w);
  *(bf16x8*)(out + i) = o;
}

// ---------------- transpose v: [b][t][d] -> [b][d][t] (bf16) ----------------
__global__ void transpose_v(const unsigned short* __restrict__ vm,
                            unsigned short* __restrict__ vT) {
  __shared__ unsigned short tile[64][72];
  int t0 = blockIdx.x * 64, d0 = blockIdx.y * 64, b = blockIdx.z;
  int tid = threadIdx.x;
  int sub = tid & 15, grp = tid >> 4;
#pragma unroll
  for (int it = 0; it < 4; ++it) {
    int tt = it * 16 + grp;
    int dd = sub * 4;
    const unsigned short* src =
        vm + ((long)(b * 2048 + t0 + tt)) * 1024 + d0 + dd;
    *(us4*)&tile[tt][dd] = *(const us4*)src;
  }
  __syncthreads();
#pragma unroll
  for (int it = 0; it < 4; ++it) {
    int dd = it * 16 + grp;
    int ts = sub * 4;
    us4 o;
    o[0] = tile[ts + 0][dd];
    o[1] = tile[ts + 1][dd];
    o[2] = tile[ts + 2][dd];
    o[3] = tile[ts + 3][dd];
    *(us4*)(vT + ((long)b * 1024 + d0 + dd) * 2048 + t0 + ts) = o;
  }
}

// ---------------- LayerNorm (in-place on f32 out) ----------------
__global__ void ln_kernel(float* __restrict__ y, const float* __restrict__ wv,
                          const float* __restrict__ bv) {
  __shared__ float sm[4];
  long row = blockIdx.x;
  int tid = threadIdx.x;
  float4 v = *(const float4*)(y + row * 1024 + tid * 4);
  float s = v.x + v.y + v.z + v.w;
#pragma unroll
  for (int o = 32; o > 0; o >>= 1) s += __shfl_xor(s, o, 64);
  if ((tid & 63) == 0) sm[tid >> 6] = s;
  __syncthreads();
  float mu = (sm[0] + sm[1] + sm[2] + sm[3]) * (1.0f / 1024.0f);
  float dx = v.x - mu, dy = v.y - mu, dz = v.z - mu, dw = v.w - mu;
  float sq = dx * dx + dy * dy + dz * dz + dw * dw;
#pragma unroll
  for (int o = 32; o > 0; o >>= 1) sq += __shfl_xor(sq, o, 64);
  __syncthreads();
  if ((tid & 63) == 0) sm[tid >> 6] = sq;
  __syncthreads();
  float var = (sm[0] + sm[1] + sm[2] + sm[3]) * (1.0f / 1024.0f);
  float inv = rsqrtf(var + 1e-5f);
  float4 w4 = *(const float4*)(wv + tid * 4);
  float4 b4 = *(const float4*)(bv + tid * 4);
  float4 o4;
  o4.x = dx * inv * w4.x + b4.x;
  o4.y = dy * inv * w4.y + b4.y;
  o4.z = dz * inv * w4.z + b4.z;
  o4.w = dw * inv * w4.w + b4.w;
  *(float4*)(y + row * 1024 + tid * 4) = o4;
}

extern "C" void kernel_launch(void* const* d_in, const int* in_sizes, int n_in,
                              void* d_out, int out_size, void* d_ws, size_t ws_size,
                              hipStream_t stream) {
  const float* x = (const float*)d_in[0];
  const float* W = (const float*)d_in[1];
  const float* bq = (const float*)d_in[2];
  const float* lnw = (const float*)d_in[3];
  const float* lnb = (const float*)d_in[4];
  float* out = (float*)d_out;

  char* ws = (char*)d_ws;
  // q[0,32M) k[32M,64M) v[64M,96M) vT[96M,128M) {xb[128M,160M) Wb[160M,166M)}
  // scores[128M,192M) aliases xb/Wb (dead after gemm1). Total 192 MiB.
  unsigned short* qb = (unsigned short*)(ws);
  unsigned short* kb = (unsigned short*)(ws + 33554432L);
  unsigned short* vb = (unsigned short*)(ws + 67108864L);
  unsigned short* vT = (unsigned short*)(ws + 100663296L);
  unsigned short* xb = (unsigned short*)(ws + 134217728L);
  unsigned short* Wb = (unsigned short*)(ws + 167772160L);
  unsigned short* sc = (unsigned short*)(ws + 134217728L);

  const float inv_scale = 1.0f / sqrtf(1024.0f * 2048.0f);

  cvt_f32_bf16<<<8192, 256, 0, stream>>>(x, xb, 16384L * 1024);
  cvt_f32_bf16<<<1536, 256, 0, stream>>>(W, Wb, 3072L * 1024);
  gemm1_qkv<<<dim3(24, 128), 256, 0, stream>>>(xb, Wb, bq, qb, kb, vb);
  transpose_v<<<dim3(32, 16, 8), 256, 0, stream>>>(vb, vT);
  gemm2_scores<<<dim3(136, 8), 256, 0, stream>>>(qb, kb, sc, inv_scale);
  gemm3_y<<<dim3(8, 16, 8), 256, 0, stream>>>(sc, vT, out);
  ln_kernel<<<16384, 256, 0, stream>>>(out, lnw, lnb);
}

// Round 8
// 396.977 us; speedup vs baseline: 2.1801x; 1.1301x over previous
//
#include <hip/hip_runtime.h>
#include <hip/hip_bf16.h>
#include <stdint.h>

typedef __attribute__((ext_vector_type(8))) short bf16x8;
typedef __attribute__((ext_vector_type(4))) float f32x4;
typedef __attribute__((ext_vector_type(4))) unsigned short us4;

__device__ __forceinline__ unsigned short f2b(float f) {
  union { float f; unsigned u; } u;
  u.f = f;
  unsigned r = u.u + 0x7fffu + ((u.u >> 16) & 1u);
  return (unsigned short)(r >> 16);
}

__device__ __forceinline__ void gload_lds16(const void* g, void* lds) {
  __builtin_amdgcn_global_load_lds(
      (const __attribute__((address_space(1))) unsigned int*)(uintptr_t)g,
      (__attribute__((address_space(3))) unsigned int*)(uintptr_t)lds,
      16, 0, 0);
}

// ===================== 128^2 m97 structure, BK=64 (2x 32-subtiles) ==========
#define TILE_M 128
#define TILE_K 32

__device__ __forceinline__ void stage_tile(const unsigned short* __restrict__ g,
                                           long ld, long row0,
                                           unsigned short* lds, int tid) {
  int w = tid >> 6, lane = tid & 63;
#pragma unroll
  for (int j = 0; j < 2; ++j) {
    int o = ((w * 2 + j) << 10) + lane * 16;
    int row = o >> 6;
    int col = (o & 63) >> 1;
    const unsigned short* gp = g + (row0 + row) * ld + col;
    gload_lds16(gp, (char*)lds + ((w * 2 + j) << 10));
  }
}

// One BK=32 sub-step: frag reads + 16 MFMA (verified m97 inner body).
__device__ __forceinline__ void mfma_step(const unsigned short* lsA,
                                          const unsigned short* lsB,
                                          int wr, int wc, int r, int g,
                                          f32x4 (&acc)[4][4]) {
  bf16x8 aF[4], bF[4];
#pragma unroll
  for (int m = 0; m < 4; ++m)
    aF[m] = *(const bf16x8*)(lsA + (wr * 64 + m * 16 + r) * 32 + g * 8);
#pragma unroll
  for (int n = 0; n < 4; ++n)
    bF[n] = *(const bf16x8*)(lsB + (wc * 64 + n * 16 + r) * 32 + g * 8);
#pragma unroll
  for (int m = 0; m < 4; ++m)
#pragma unroll
    for (int n = 0; n < 4; ++n)
      acc[m][n] = __builtin_amdgcn_mfma_f32_16x16x32_bf16(aF[m], bF[n], acc[m][n], 0, 0, 0);
}

// gemm1: qkv = x @ W^T + b. q/k deinterleaved row-major; v written TRANSPOSED
// directly to vT[b][d][t] (fuses transpose_v).
__global__ __launch_bounds__(256, 2) void gemm1_qkv(
    const unsigned short* __restrict__ A,   // x bf16 [16384][1024]
    const unsigned short* __restrict__ Bm,  // W bf16 [3072][1024]
    const float* __restrict__ bias,         // [3072] f32
    unsigned short* __restrict__ qb, unsigned short* __restrict__ kb,
    unsigned short* __restrict__ vT) {      // vT bf16 [8][1024][2048]
  __shared__ unsigned short lsA[2][TILE_M * TILE_K];
  __shared__ unsigned short lsB[2][TILE_M * TILE_K];
  int tid = threadIdx.x;
  int lane = tid & 63, w = tid >> 6;
  int wr = w >> 1, wc = w & 1;
  long bm0 = (long)blockIdx.y * TILE_M;
  long bn0 = (long)blockIdx.x * TILE_M;
  f32x4 acc[4][4] = {};
  int r = lane & 15, g = lane >> 4;
  for (int kt = 0; kt < 1024 / 64; ++kt) {
    long k0 = (long)kt * 64;
    stage_tile(A + k0, 1024, bm0, lsA[0], tid);
    stage_tile(A + k0 + 32, 1024, bm0, lsA[1], tid);
    stage_tile(Bm + k0, 1024, bn0, lsB[0], tid);
    stage_tile(Bm + k0 + 32, 1024, bn0, lsB[1], tid);
    __syncthreads();
    mfma_step(lsA[0], lsB[0], wr, wc, r, g, acc);
    mfma_step(lsA[1], lsB[1], wr, wc, r, g, acc);
    __syncthreads();
  }
  int part = blockIdx.x >> 3;  // 0=q 1=k 2=v
  long cl0 = (long)(blockIdx.x & 7) * 128;
  if (part < 2) {
    unsigned short* O = (part == 0) ? qb : kb;
#pragma unroll
    for (int n = 0; n < 4; ++n) {
      long cc = wc * 64 + n * 16 + r;
      float bv = bias[bn0 + cc];
#pragma unroll
      for (int m = 0; m < 4; ++m)
#pragma unroll
        for (int j = 0; j < 4; ++j) {
          long row = bm0 + wr * 64 + m * 16 + g * 4 + j;
          O[row * 1024 + cl0 + cc] = f2b(acc[m][n][j] + bv);
        }
    }
  } else {
    // v: write transposed. global row R = bm0 + roff, b = R>>11, t = R&2047.
    long bq = bm0 >> 11;            // batch (tiles never straddle: 2048 % 128 == 0)
    long tbase = bm0 & 2047;
#pragma unroll
    for (int n = 0; n < 4; ++n) {
      long cc = wc * 64 + n * 16 + r;
      float bv = bias[bn0 + cc];
      long d = cl0 + cc;
#pragma unroll
      for (int m = 0; m < 4; ++m) {
        long t = tbase + wr * 64 + m * 16 + g * 4;
        us4 o;
        o[0] = f2b(acc[m][n][0] + bv);
        o[1] = f2b(acc[m][n][1] + bv);
        o[2] = f2b(acc[m][n][2] + bv);
        o[3] = f2b(acc[m][n][3] + bv);
        *(us4*)(vT + bq * 2097152 + d * 2048 + t) = o;
      }
    }
  }
}

// gemm2: scores = tril(q k^T) * inv_scale; grid.x = 136 lower-tri tiles.
__global__ __launch_bounds__(256, 2) void gemm2_scores(
    const unsigned short* __restrict__ qm, const unsigned short* __restrict__ km,
    unsigned short* __restrict__ scores, float inv_scale) {
  __shared__ unsigned short lsA[2][TILE_M * TILE_K];
  __shared__ unsigned short lsB[2][TILE_M * TILE_K];
  int p = 135 - blockIdx.x;  // heavy-first
  int bi = 0, base = 0;
  while (p >= base + bi + 1) { base += bi + 1; ++bi; }
  int bj = p - base;
  int b = blockIdx.y;
  int tid = threadIdx.x;
  int lane = tid & 63, w = tid >> 6;
  int wr = w >> 1, wc = w & 1;
  long bm0 = (long)bi * TILE_M;
  long bn0 = (long)bj * TILE_M;
  const unsigned short* A = qm + (long)b * 2048 * 1024;
  const unsigned short* Bm = km + (long)b * 2048 * 1024;
  f32x4 acc[4][4] = {};
  int r = lane & 15, g = lane >> 4;
  for (int kt = 0; kt < 1024 / 64; ++kt) {
    long k0 = (long)kt * 64;
    stage_tile(A + k0, 1024, bm0, lsA[0], tid);
    stage_tile(A + k0 + 32, 1024, bm0, lsA[1], tid);
    stage_tile(Bm + k0, 1024, bn0, lsB[0], tid);
    stage_tile(Bm + k0 + 32, 1024, bn0, lsB[1], tid);
    __syncthreads();
    mfma_step(lsA[0], lsB[0], wr, wc, r, g, acc);
    mfma_step(lsA[1], lsB[1], wr, wc, r, g, acc);
    __syncthreads();
  }
  unsigned short* S = scores + (long)b * 2048 * 2048;
#pragma unroll
  for (int n = 0; n < 4; ++n) {
    long col = bn0 + wc * 64 + n * 16 + r;
#pragma unroll
    for (int m = 0; m < 4; ++m)
#pragma unroll
      for (int j = 0; j < 4; ++j) {
        long row = bm0 + wr * 64 + m * 16 + g * 4 + j;
        float v = acc[m][n][j] * inv_scale;
        if (col > row) v = 0.0f;
        S[row * 2048 + col] = f2b(v);
      }
  }
}

// gemm3: y = scores @ v (f32 out), causal K, heavy-first bi.
__global__ __launch_bounds__(256, 2) void gemm3_y(
    const unsigned short* __restrict__ scores, const unsigned short* __restrict__ vT,
    float* __restrict__ out) {
  __shared__ unsigned short lsA[2][TILE_M * TILE_K];
  __shared__ unsigned short lsB[2][TILE_M * TILE_K];
  int bn = blockIdx.x, bi = 15 - blockIdx.y, b = blockIdx.z;
  int tid = threadIdx.x;
  int lane = tid & 63, w = tid >> 6;
  int wr = w >> 1, wc = w & 1;
  long bm0 = (long)bi * TILE_M;
  long bn0 = (long)bn * TILE_M;
  const unsigned short* A = scores + (long)b * 2048 * 2048;
  const unsigned short* Bm = vT + (long)b * 1024 * 2048;
  f32x4 acc[4][4] = {};
  int r = lane & 15, g = lane >> 4;
  int KT2 = (bi + 1) * 2;  // 64-wide K-steps up to the diagonal
  for (int kt = 0; kt < KT2; ++kt) {
    long k0 = (long)kt * 64;
    stage_tile(A + k0, 2048, bm0, lsA[0], tid);
    stage_tile(A + k0 + 32, 2048, bm0, lsA[1], tid);
    stage_tile(Bm + k0, 2048, bn0, lsB[0], tid);
    stage_tile(Bm + k0 + 32, 2048, bn0, lsB[1], tid);
    __syncthreads();
    mfma_step(lsA[0], lsB[0], wr, wc, r, g, acc);
    mfma_step(lsA[1], lsB[1], wr, wc, r, g, acc);
    __syncthreads();
  }
#pragma unroll
  for (int n = 0; n < 4; ++n) {
    long col = bn0 + wc * 64 + n * 16 + r;
#pragma unroll
    for (int m = 0; m < 4; ++m)
#pragma unroll
      for (int j = 0; j < 4; ++j) {
        long row = bm0 + wr * 64 + m * 16 + g * 4 + j;
        out[((long)b * 2048 + row) * 1024 + col] = acc[m][n][j];
      }
  }
}

// ---------------- f32 -> bf16 conversion (x and W in one launch) ----------------
__global__ void cvt_f32_bf16(const float* __restrict__ x, unsigned short* __restrict__ xb,
                             const float* __restrict__ W, unsigned short* __restrict__ Wb) {
  const long n1 = 16384L * 1024;  // x elements
  const long n2 = 3072L * 1024;   // W elements
  long i = ((long)blockIdx.x * blockDim.x + threadIdx.x) * 8;
  const float* in;
  unsigned short* out;
  if (i < n1) { in = x + i; out = xb + i; }
  else {
    long k = i - n1;
    if (k >= n2) return;
    in = W + k; out = Wb + k;
  }
  float4 a = *(const float4*)(in);
  float4 b = *(const float4*)(in + 4);
  bf16x8 o;
  o[0] = (short)f2b(a.x); o[1] = (short)f2b(a.y);
  o[2] = (short)f2b(a.z); o[3] = (short)f2b(a.w);
  o[4] = (short)f2b(b.x); o[5] = (short)f2b(b.y);
  o[6] = (short)f2b(b.z); o[7] = (short)f2b(b.w);
  *(bf16x8*)(out) = o;
}

// ---------------- LayerNorm (in-place on f32 out) ----------------
__global__ void ln_kernel(float* __restrict__ y, const float* __restrict__ wv,
                          const float* __restrict__ bv) {
  __shared__ float sm[4];
  long row = blockIdx.x;
  int tid = threadIdx.x;
  float4 v = *(const float4*)(y + row * 1024 + tid * 4);
  float s = v.x + v.y + v.z + v.w;
#pragma unroll
  for (int o = 32; o > 0; o >>= 1) s += __shfl_xor(s, o, 64);
  if ((tid & 63) == 0) sm[tid >> 6] = s;
  __syncthreads();
  float mu = (sm[0] + sm[1] + sm[2] + sm[3]) * (1.0f / 1024.0f);
  float dx = v.x - mu, dy = v.y - mu, dz = v.z - mu, dw = v.w - mu;
  float sq = dx * dx + dy * dy + dz * dz + dw * dw;
#pragma unroll
  for (int o = 32; o > 0; o >>= 1) sq += __shfl_xor(sq, o, 64);
  __syncthreads();
  if ((tid & 63) == 0) sm[tid >> 6] = sq;
  __syncthreads();
  float var = (sm[0] + sm[1] + sm[2] + sm[3]) * (1.0f / 1024.0f);
  float inv = rsqrtf(var + 1e-5f);
  float4 w4 = *(const float4*)(wv + tid * 4);
  float4 b4 = *(const float4*)(bv + tid * 4);
  float4 o4;
  o4.x = dx * inv * w4.x + b4.x;
  o4.y = dy * inv * w4.y + b4.y;
  o4.z = dz * inv * w4.z + b4.z;
  o4.w = dw * inv * w4.w + b4.w;
  *(float4*)(y + row * 1024 + tid * 4) = o4;
}

extern "C" void kernel_launch(void* const* d_in, const int* in_sizes, int n_in,
                              void* d_out, int out_size, void* d_ws, size_t ws_size,
                              hipStream_t stream) {
  const float* x = (const float*)d_in[0];
  const float* W = (const float*)d_in[1];
  const float* bq = (const float*)d_in[2];
  const float* lnw = (const float*)d_in[3];
  const float* lnb = (const float*)d_in[4];
  float* out = (float*)d_out;

  char* ws = (char*)d_ws;
  // q[0,32M) k[32M,64M) vT[96M,128M) {xb[128M,160M) Wb[160M,166M)}
  // scores[128M,192M) aliases xb/Wb (dead after gemm1). Total 192 MiB.
  unsigned short* qb = (unsigned short*)(ws);
  unsigned short* kb = (unsigned short*)(ws + 33554432L);
  unsigned short* vT = (unsigned short*)(ws + 100663296L);
  unsigned short* xb = (unsigned short*)(ws + 134217728L);
  unsigned short* Wb = (unsigned short*)(ws + 167772160L);
  unsigned short* sc = (unsigned short*)(ws + 134217728L);

  const float inv_scale = 1.0f / sqrtf(1024.0f * 2048.0f);

  cvt_f32_bf16<<<9728, 256, 0, stream>>>(x, xb, W, Wb);  // (16M+3M)/8/256
  gemm1_qkv<<<dim3(24, 128), 256, 0, stream>>>(xb, Wb, bq, qb, kb, vT);
  gemm2_scores<<<dim3(136, 8), 256, 0, stream>>>(qb, kb, sc, inv_scale);
  gemm3_y<<<dim3(8, 16, 8), 256, 0, stream>>>(sc, vT, out);
  ln_kernel<<<16384, 256, 0, stream>>>(out, lnw, lnb);
}